// Round 11
// baseline (178.387 us; speedup 1.0000x reference)
//
#include <hip/hip_runtime.h>
#include <math.h>

#define HDIM 2048
#define WDIM 2048
#define NPIX (HDIM*WDIM)
#define OUTW 2038          /* valid conv output size: 2048-10 */

#define C1F 6.5025f        /* (0.01*255)^2 */
#define C2F 58.5225f       /* (0.03*255)^2 */

constexpr int TH   = 64, TW = 32;  // output tile
constexpr int S_ROWS = 80;         // staged rows
constexpr int S_CDW  = 48;         // staged f32 cols
constexpr int S_IMG  = S_ROWS * S_CDW;   // 3840 f32 = 15360 B per image
constexpr int HT_R = 80;           // HT row stride: [arr][col][row]
constexpr int HT_A = 32 * HT_R;    // 2560 f16 per array
constexpr int NCH  = 4;            // mu1, mu2, (p^2+t^2)/4, p*t
constexpr int NBLK = 8192;         // 64 x 32 x 4 blocks

struct GaussW { float g[11]; };

typedef _Float16 half8 __attribute__((ext_vector_type(8)));
typedef float    f32x4 __attribute__((ext_vector_type(4)));
typedef float    f32x2 __attribute__((ext_vector_type(2)));

// async global->LDS staging: no dest register => compiler cannot spill or
// per-load-serialize it; 30 wave-instrs issue back-to-back, ONE drain.
// LDS dest = wave-uniform base + lane*16 (m104), so lp must be wave-uniform.
#define GLDS16(gp, lp) \
    __builtin_amdgcn_global_load_lds( \
        (const __attribute__((address_space(1))) void*)(gp), \
        (__attribute__((address_space(3))) void*)(lp), 16, 0, 0)

// quant: bit-exact vs reference sequence. (clip(x)+1)*0.5 then *255 ==
// (clip(x)+1)*127.5; trunc == floor for v >= 0. Must stay add-then-mul.
__device__ __forceinline__ float quant_u8f(float x) {
    float c = __builtin_amdgcn_fmed3f(x, -1.0f, 1.0f);
    return truncf((c + 1.0f) * 127.5f);
}
__device__ __forceinline__ f32x2 quant2(f32x2 x) {
    f32x2 c = { __builtin_amdgcn_fmed3f(x.x, -1.0f, 1.0f),
                __builtin_amdgcn_fmed3f(x.y, -1.0f, 1.0f) };
    f32x2 v = (c + 1.0f) * 127.5f;     // pk_add then pk_mul: matches reference
    return { truncf(v.x), truncf(v.y) };
}
__device__ __forceinline__ unsigned pk2(float a, float b) {
    return __builtin_bit_cast(unsigned, __builtin_amdgcn_cvt_pkrtz(a, b));
}
// 8 f32 -> quantized half8 (values are exact integers 0..255; rtz pack exact)
__device__ __forceinline__ half8 quant8(float4 lo, float4 hi) {
    union { unsigned u[4]; half8 h; } r;
    r.u[0] = pk2(quant_u8f(lo.x), quant_u8f(lo.y));
    r.u[1] = pk2(quant_u8f(lo.z), quant_u8f(lo.w));
    r.u[2] = pk2(quant_u8f(hi.x), quant_u8f(hi.y));
    r.u[3] = pk2(quant_u8f(hi.z), quant_u8f(hi.w));
    return r.h;
}

// ---------------------------------------------------------------------------
// Fused kernel (round 18: global_load_lds staging -- the MLP fix).
//   r5/r8/r9 lesson: register-dest loads are ALWAYS serialized (spill/drain
//   forces per-load waitcnt; __syncthreads drains vmcnt(0)). global_load_lds
//   has no dest register -> fire-and-forget, 30 instrs in flight per block.
//   Staging: raw f32 [2img][80][48] linear in LDS (clamped global addrs);
//   stats + H-fragments read from LDS; Iq eliminated; HT aliases staging
//   after register preload. Clamped rows make boundary gx terms vanish
//   exactly -> ONE uniform stats path for all blocks.
// Channels: 0:l1 1:gxH 2:gyW 3:relu 4:sp 5:st 6:spp 7:stt 8:su8 9:ssim
// ---------------------------------------------------------------------------
__global__ __launch_bounds__(256, 5) void amsr2_fused(
        const float* __restrict__ pred, const float* __restrict__ targ,
        float* __restrict__ pr, GaussW gw)
{
    __shared__ alignas(16) float Stg[2 * S_IMG];      // 30720 B; HT overlays
    __shared__ alignas(16) _Float16 Tg[16 * 32];      // 1024 B, persistent
    __shared__ float sred[16][10];
    _Float16* HTp = (_Float16*)Stg;                   // 4*2560*2 = 20480 B

    const int tid  = threadIdx.x;
    const int lane = tid & 63;
    const int wid  = tid >> 6;
    const int q    = lane >> 4;
    const int ml   = lane & 15;

    const int b  = blockIdx.z;
    const int r0 = blockIdx.y * TH;
    const int c0 = blockIdx.x * TW;
    const float* pb = pred + (size_t)b * NPIX;
    const float* tb = targ + (size_t)b * NPIX;
    const bool interior = (blockIdx.y < 31) && (blockIdx.x < 63);
    const bool lastcol  = (blockIdx.x == 63);

    // ---- banded Gaussian table (threads 0..15) ----
    if (tid < 16) {
        int n = tid;
#pragma unroll
        for (int i = 0; i < 16; ++i) ((unsigned*)Tg)[n * 16 + i] = 0u;
#pragma unroll
        for (int j = 0; j < 11; ++j) Tg[n * 32 + n + j] = (_Float16)gw.g[j];
    }

    // ---- staging: 1920 x 16B items, linear LDS, clamped global addrs ----
    // item = img*960 + row*12 + c16; LDS byte = item*16.
#pragma unroll
    for (int j = 0; j < 8; ++j) {
        if (j < 7 || tid < 128) {            // wave-uniform tail guard
            int item = j * 256 + tid;
            int img  = item >= 960 ? 1 : 0;
            int wi   = item - img * 960;
            int row  = wi / 12;
            int c16  = wi - row * 12;
            int gr = r0 + row; if (gr > HDIM - 1) gr = HDIM - 1;
            int gc = c0 + c16 * 4; if (gc > WDIM - 4) gc = WDIM - 4;
            const float* gp = (img ? tb : pb) + (size_t)gr * WDIM + gc;
            unsigned lofs = (unsigned)(j * 256 + (tid & ~63)) * 16u;
            GLDS16(gp, (char*)Stg + lofs);
        }
    }
    asm volatile("s_waitcnt vmcnt(0)" ::: "memory");
    __syncthreads();

    // ---- stats from LDS: uniform path for ALL blocks (clamp => boundary
    //      gx terms vanish exactly; only chunk-granular right edge guarded) --
    float s0 = 0.f, s1 = 0.f, s2 = 0.f, s3 = 0.f, ssum = 0.f;
    f32x2 s4v = {0,0}, s5v = {0,0}, s6v = {0,0},
          s7v = {0,0}, s8v = {0,0}, ssv = {0,0};
#pragma unroll
    for (int i = 0; i < 2; ++i) {
        int item = tid + i * 256;
        int r = item >> 3, d = item & 7;
        const float* pA = &Stg[r * S_CDW + d * 4];
        const float* pB = &Stg[S_IMG + r * S_CDW + d * 4];
        float4 a4 = *(const float4*)pA;
        float4 b4 = *(const float4*)pB;
        float4 ad = *(const float4*)(pA + S_CDW);   // row+1 (staged/clamped)
        float4 bd = *(const float4*)(pB + S_CDW);
        float p5 = pA[4], t5 = pB[4];

        f32x2 a01 = {a4.x, a4.y}, a23 = {a4.z, a4.w};
        f32x2 b01 = {b4.x, b4.y}, b23 = {b4.z, b4.w};
        f32x2 dd01 = a01 - b01, dd23 = a23 - b23;
        f32x2 g01 = f32x2{ad.x, ad.y} - f32x2{bd.x, bd.y};
        f32x2 g23 = f32x2{ad.z, ad.w} - f32x2{bd.z, bd.w};
        // right-edge: col clamp is 16B-granular, so guard the d==7 term
        bool hasR = !(lastcol && d == 7);
        float dd4 = hasR ? (p5 - t5) : dd23.y;      // !hasR => term = 0

        s0 += fabsf(dd01.x); s0 += fabsf(dd01.y);
        s0 += fabsf(dd23.x); s0 += fabsf(dd23.y);
        s1 += fabsf(dd01.x - g01.x); s1 += fabsf(dd01.y - g01.y);
        s1 += fabsf(dd23.x - g23.x); s1 += fabsf(dd23.y - g23.y);
        s2 += fabsf(dd01.x - dd01.y); s2 += fabsf(dd01.y - dd23.x);
        s2 += fabsf(dd23.x - dd23.y); s2 += fabsf(dd23.y - dd4);
        s3 += fmaxf(fabsf(a4.x) - 1.0f, 0.0f);
        s3 += fmaxf(fabsf(a4.y) - 1.0f, 0.0f);
        s3 += fmaxf(fabsf(a4.z) - 1.0f, 0.0f);
        s3 += fmaxf(fabsf(a4.w) - 1.0f, 0.0f);
        s4v += a01; s4v += a23;
        s5v += b01; s5v += b23;
        s6v += a01 * a01; s6v += a23 * a23;
        s7v += b01 * b01; s7v += b23 * b23;
        f32x2 qp01 = quant2(a01), qp23 = quant2(a23);
        f32x2 qt01 = quant2(b01), qt23 = quant2(b23);
        f32x2 qd01 = qp01 - qt01, qd23 = qp23 - qt23;
        s8v += qd01 * qd01; s8v += qd23 * qd23;
    }

    // ---- H fragment preload: read raw f32 from LDS, quantize in-register --
    const half8 gfrag = *(const half8*)&Tg[ml * 32 + q * 8];
    const f32x4 zero4 = {0.f, 0.f, 0.f, 0.f};
    const _Float16 hquart = (_Float16)0.25f;
    const int npos = (wid < 2) ? 3 : 2;
    half8 hap[3], hat[3];
#pragma unroll
    for (int i = 0; i < 3; ++i) {
        if (i < npos) {
            int pos = wid + i * 4;
            int rb = (pos >> 1) * 16;
            int cb = pos & 1;
            int row = rb + ml, cf = cb * 16 + q * 8;
            const float* pA = &Stg[row * S_CDW + cf];
            const float* pB = &Stg[S_IMG + row * S_CDW + cf];
            float4 x0 = *(const float4*)pA, x1 = *(const float4*)(pA + 4);
            float4 y0 = *(const float4*)pB, y1 = *(const float4*)(pB + 4);
            hap[i] = quant8(x0, x1);
            hat[i] = quant8(y0, y1);
        }
    }
    __syncthreads();   // all Stg reads done -> HT may overwrite staging

    // ---- stage H: horizontal conv via MFMA; HT[arr][col][row] over Stg ----
#pragma unroll
    for (int i = 0; i < 3; ++i) {
        if (i < npos) {
            int pos = wid + i * 4;
            int rb = (pos >> 1) * 16;
            int cb = pos & 1;
            const half8 ap = hap[i];
            const half8 at = hat[i];
            half8 m2 = (ap * hquart) * ap;
            m2 = (at * hquart) * at + m2;
            f32x4 d0 = __builtin_amdgcn_mfma_f32_16x16x32_f16(ap,      gfrag, zero4, 0, 0, 0);
            f32x4 d1 = __builtin_amdgcn_mfma_f32_16x16x32_f16(at,      gfrag, zero4, 0, 0, 0);
            f32x4 d2 = __builtin_amdgcn_mfma_f32_16x16x32_f16(m2,      gfrag, zero4, 0, 0, 0);
            f32x4 d3 = __builtin_amdgcn_mfma_f32_16x16x32_f16(ap * at, gfrag, zero4, 0, 0, 0);
            int hb = (cb * 16 + ml) * HT_R + rb + q * 4;
            *(uint2*)&HTp[0 * HT_A + hb] = make_uint2(pk2(d0[0], d0[1]), pk2(d0[2], d0[3]));
            *(uint2*)&HTp[1 * HT_A + hb] = make_uint2(pk2(d1[0], d1[1]), pk2(d1[2], d1[3]));
            *(uint2*)&HTp[2 * HT_A + hb] = make_uint2(pk2(d2[0], d2[1]), pk2(d2[2], d2[3]));
            *(uint2*)&HTp[3 * HT_A + hb] = make_uint2(pk2(d3[0], d3[1]), pk2(d3[2], d3[3]));
        }
    }
    __syncthreads();

    // ---- stage V: vertical conv via MFMA + SSIM map ----
    const int th_ = min(TH, OUTW - r0);
    const int tw_ = min(TW, OUTW - c0);
    for (int vp = wid; vp < 8; vp += 4) {
        int rb2 = (vp >> 1) * 16;
        int cb2 = vp & 1;
        f32x4 acc[NCH];
#pragma unroll
        for (int arr = 0; arr < NCH; ++arr) {
            const half8 bf = *(const half8*)&HTp[arr * HT_A +
                                                 (cb2 * 16 + ml) * HT_R + rb2 + q * 8];
            acc[arr] = __builtin_amdgcn_mfma_f32_16x16x32_f16(gfrag, bf, zero4, 0, 0, 0);
        }
        if (interior) {
#pragma unroll
            for (int pp = 0; pp < 2; ++pp) {
                f32x2 mu1 = {acc[0][2*pp], acc[0][2*pp+1]};
                f32x2 mu2 = {acc[1][2*pp], acc[1][2*pp+1]};
                f32x2 h2  = {acc[2][2*pp], acc[2][2*pp+1]};
                f32x2 h12 = {acc[3][2*pp], acc[3][2*pp+1]};
                f32x2 mu12 = mu1 * mu2, mu1s = mu1 * mu1, mu2s = mu2 * mu2;
                f32x2 sg12 = h12 - mu12;
                f32x2 sgs  = 4.0f * h2 - mu1s - mu2s;
                f32x2 num = (2.0f * mu12 + C1F) * (2.0f * sg12 + C2F);
                f32x2 den = (mu1s + mu2s + C1F) * (sgs + C2F);
                f32x2 rp = { __builtin_amdgcn_rcpf(den.x),
                             __builtin_amdgcn_rcpf(den.y) };
                ssv += num * rp;
            }
        } else {
            int col = cb2 * 16 + ml;
#pragma unroll
            for (int reg = 0; reg < 4; ++reg) {
                int row = rb2 + q * 4 + reg;
                if (row < th_ && col < tw_) {
                    float mu1 = acc[0][reg], mu2 = acc[1][reg];
                    float h2  = acc[2][reg], h12 = acc[3][reg];
                    float mu1s = mu1 * mu1, mu2s = mu2 * mu2, mu12 = mu1 * mu2;
                    float sg12 = h12 - mu12;
                    float sgs  = 4.0f * h2 - mu1s - mu2s;
                    float num = (2.0f * mu12 + C1F) * (2.0f * sg12 + C2F);
                    float den = (mu1s + mu2s + C1F) * (sgs + C2F);
                    ssum += num * __builtin_amdgcn_rcpf(den);
                }
            }
        }
    }

    // ---- block reduction: 4-level xor tree within 16-lane groups ----
    float st10[10];
    st10[0] = s0; st10[1] = s1; st10[2] = s2; st10[3] = s3;
    st10[4] = s4v.x + s4v.y; st10[5] = s5v.x + s5v.y;
    st10[6] = s6v.x + s6v.y; st10[7] = s7v.x + s7v.y;
    st10[8] = s8v.x + s8v.y; st10[9] = ssum + ssv.x + ssv.y;
#pragma unroll
    for (int c = 0; c < 10; ++c) {
        float v = st10[c];
        v += __shfl_xor(v, 8);
        v += __shfl_xor(v, 4);
        v += __shfl_xor(v, 2);
        v += __shfl_xor(v, 1);
        st10[c] = v;
    }
    if ((lane & 15) == 0) {
        int g = wid * 4 + (lane >> 4);
#pragma unroll
        for (int c = 0; c < 10; ++c) sred[g][c] = st10[c];
    }
    __syncthreads();
    if (tid < 10) {
        int c = tid;
        float t = 0.0f;
#pragma unroll
        for (int g = 0; g < 16; ++g) t += sred[g][c];
        int bid = ((b * 32) + blockIdx.y) * 64 + blockIdx.x;
        pr[c * NBLK + bid] = t;
    }
}

// ---------------------------------------------------------------------------
// Final: ONE block. 40 segments of 2048 contiguous floats, coalesced float4
// reads, f64 shfl-reduce; thread 0 does the scalar combine.
// ---------------------------------------------------------------------------
__global__ __launch_bounds__(256) void amsr2_final(
        const float* __restrict__ pr, float* __restrict__ out)
{
    __shared__ double seg[40];
    int wid = threadIdx.x >> 6, lane = threadIdx.x & 63;
    for (int sidx = wid; sidx < 40; sidx += 4) {
        int c = sidx >> 2, b = sidx & 3;
        const float* base = pr + c * NBLK + b * 2048;
        float4 v[8];
#pragma unroll
        for (int it = 0; it < 8; ++it)
            v[it] = *(const float4*)(base + (it * 64 + lane) * 4);
        double acc = 0.0;
#pragma unroll
        for (int it = 0; it < 8; ++it)
            acc += (double)v[it].x + (double)v[it].y + (double)v[it].z + (double)v[it].w;
        for (int off = 32; off > 0; off >>= 1) acc += __shfl_down(acc, off);
        if (lane == 0) seg[sidx] = acc;
    }
    __syncthreads();
    if (threadIdx.x != 0) return;
    const double n = (double)NPIX;
    double sum0 = 0, sum1 = 0, sum2 = 0, sum3 = 0;
    for (int b = 0; b < 4; ++b) {
        sum0 += seg[0*4+b]; sum1 += seg[1*4+b]; sum2 += seg[2*4+b]; sum3 += seg[3*4+b];
    }
    double l1   = sum0 / (4.0 * n);
    double grad = sum1 / (4.0 * 2047.0 * 2048.0) + sum2 / (4.0 * 2048.0 * 2047.0);
    double energy = 0.0, dist = 0.0, psnr_sum = 0.0, ssim_sum = 0.0;
    for (int b = 0; b < 4; ++b) {
        double Sp  = seg[4*4+b],  St  = seg[5*4+b];
        double Spp = seg[6*4+b],  Stt = seg[7*4+b];
        double Su8 = seg[8*4+b],  Sss = seg[9*4+b];
        double pm = Sp / n, tm = St / n;
        double dm = pm - tm; energy += dm * dm;
        double vp = (Spp - n * pm * pm) / (n - 1.0);
        double vt = (Stt - n * tm * tm) / (n - 1.0);
        double ps = sqrt(fmax(vp, 0.0)), ts = sqrt(fmax(vt, 0.0));
        double dd = ps - ts; dist += dd * dd;
        double mse = Su8 / n;
        double psnr = (mse == 0.0) ? 100.0 : 10.0 * log10(65025.0 / fmax(mse, 1e-12));
        psnr_sum += psnr;
        ssim_sum += Sss / ((double)OUTW * (double)OUTW);
    }
    energy *= 0.25; dist *= 0.25;
    double range_pen = sum3 / (4.0 * n);
    double phys = energy + 0.5 * dist + 0.1 * range_pen;
    double ssim_mean = fmin(fmax(ssim_sum * 0.25, 0.0), 1.0);
    double total = l1 + 0.15 * grad + 0.05 * phys + 0.1 * (1.0 - ssim_mean);
    out[0] = (float)total;
    out[1] = (float)(psnr_sum * 0.25);
    out[2] = (float)ssim_mean;
}

extern "C" void kernel_launch(void* const* d_in, const int* in_sizes, int n_in,
                              void* d_out, int out_size, void* d_ws, size_t ws_size,
                              hipStream_t stream)
{
    (void)in_sizes; (void)n_in; (void)out_size; (void)ws_size;
    const float* pred = (const float*)d_in[0];
    const float* targ = (const float*)d_in[1];
    float* out = (float*)d_out;
    float* pr  = (float*)d_ws;            // 10 * 8192 floats of per-block partials

    GaussW gw;                            // host-side f64 Gaussian, cast to f32
    {
        double e[11], sm = 0.0;
        for (int i = 0; i < 11; ++i) {
            double d = (double)(i - 5);
            e[i] = exp(-(d * d) / 4.5);
            sm += e[i];
        }
        for (int i = 0; i < 11; ++i) gw.g[i] = (float)(e[i] / sm);
    }

    amsr2_fused<<<dim3(64, 32, 4), 256, 0, stream>>>(pred, targ, pr, gw);
    amsr2_final<<<1, 256, 0, stream>>>(pr, out);
}